// Round 10
// baseline (27.173 us; speedup 1.0000x reference)
//
#include <hip/hip_runtime.h>
#include <math.h>

typedef float v2f __attribute__((ext_vector_type(2)));

#define FOUR_PI 12.566370614359172f
#define YIM  (-(FOUR_PI * 1e-9f))   // constant imag part of k^2 argument
#define YABS (FOUR_PI * 1e-9f)
#define LOG2E  1.4426950408889634f
#define LN2    0.6931471805599453f
#define INV2PI 0.15915494309189535f

__device__ __forceinline__ float frcp(float x) { return __builtin_amdgcn_rcpf(x); }
__device__ __forceinline__ float frsq(float x) { return __builtin_amdgcn_rsqf(x); }

#if __has_builtin(__builtin_amdgcn_exp2f)
__device__ __forceinline__ float fexp2(float x) { return __builtin_amdgcn_exp2f(x); }
#else
__device__ __forceinline__ float fexp2(float x) { return exp2f(x); }
#endif
#if __has_builtin(__builtin_amdgcn_sinf) && __has_builtin(__builtin_amdgcn_cosf)
__device__ __forceinline__ float fsin_rev(float x) { return __builtin_amdgcn_sinf(x); }
__device__ __forceinline__ float fcos_rev(float x) { return __builtin_amdgcn_cosf(x); }
#else
__device__ __forceinline__ float fsin_rev(float x) { return __sinf(x * 6.283185307179586f); }
__device__ __forceinline__ float fcos_rev(float x) { return __cosf(x * 6.283185307179586f); }
#endif
#if __has_builtin(__builtin_amdgcn_fractf)
__device__ __forceinline__ float ffract(float x) { return __builtin_amdgcn_fractf(x); }
#else
__device__ __forceinline__ float ffract(float x) { return x - floorf(x); }
#endif

__device__ __forceinline__ v2f vfma(v2f a, v2f b, v2f c) { return __builtin_elementwise_fma(a, b, c); }
__device__ __forceinline__ v2f vabs(v2f a) { return __builtin_elementwise_abs(a); }
__device__ __forceinline__ v2f vmax2(v2f a, v2f b) { v2f r; r.x = fmaxf(a.x, b.x); r.y = fmaxf(a.y, b.y); return r; }

// packed principal sqrt of (x + i*YIM), YIM < 0 constant; no v_sqrt:
// r = sqrt(x^2+Y^2) ~= max(|x|, (|x|+|Y|)/2)  (exact at x=0 and |x|>>|Y|).
__device__ __forceinline__ void csqrt2(v2f x, v2f& u, v2f& v) {
    v2f ax = vabs(x);
    v2f h  = vmax2(ax, vfma(ax, (v2f)0.5f, (v2f)(0.5f * YABS)));  // (r+|x|)/2
    v2f irs; irs.x = frsq(h.x); irs.y = frsq(h.y);
    v2f w = h * irs;                 // sqrt(h), large component > 0
    v2f o = (0.5f * YIM) * irs;      // small component <= 0
    u.x = (x.x >= 0.0f) ? w.x : -o.x;
    v.x = (x.x >= 0.0f) ? o.x : -w.x;
    u.y = (x.y >= 0.0f) ? w.y : -o.y;
    v.y = (x.y >= 0.0f) ? o.y : -w.y;
}

__global__ __launch_bounds__(256, 2) void abeles_kernel(
    const float* __restrict__ qarr,   // B*Q
    const float* __restrict__ thick,  // B*L
    const float* __restrict__ rough,  // B*L
    const float* __restrict__ sld,    // B*(L+1)
    float* __restrict__ out,          // B*Q
    int Q, int L)
{
    const int b  = blockIdx.y;
    const int tx = threadIdx.x;

    __shared__ float4 s_pk[64];   // { 2t*log2e, 2t/(2pi), -2s^2*log2e, xp_j }
    __shared__ float  s_xpL;      // xp at the substrate (layer L)

    {
        float s0 = sld[(size_t)b * (L + 1)];
        for (int i = tx; i < L; i += blockDim.x) {
            float t  = thick[(size_t)b * L + i];
            float sg = rough[(size_t)b * L + i];
            float s2 = sg * sg;
            float xp = (FOUR_PI * 1e-6f) * (sld[(size_t)b * (L + 1) + i] - s0);
            s_pk[i] = make_float4(2.0f * t * LOG2E, 2.0f * t * INV2PI,
                                  -2.0f * s2 * LOG2E, xp);
        }
        if (tx == 0)
            s_xpL = (FOUR_PI * 1e-6f) * (sld[(size_t)b * (L + 1) + L] - s0);
    }

    // two q-chains per thread, packed in .x/.y
    const int iq0 = blockIdx.x * (2 * blockDim.x) + tx;
    const int iq1 = iq0 + blockDim.x;
    float qa = (iq0 < Q) ? qarr[(size_t)b * Q + iq0] : 0.1f;
    float qb = (iq1 < Q) ? qarr[(size_t)b * Q + iq1] : 0.1f;
    v2f q2; q2.x = 0.25f * qa * qa; q2.y = 0.25f * qb * qb;
    __syncthreads();

    // carried k = substrate; R = N/D, N=0, D=1
    v2f cu, cv;
    csqrt2(q2 - s_xpL, cu, cv);
    v2f Nr = (v2f)0.0f, Ni = (v2f)0.0f, Dr = (v2f)1.0f, Di = (v2f)0.0f;

    int j = L;
    while (j >= 8) {
        const int g = j - 8;

        // ---- stage 8 layers' params into regs (one b128 each)
        float4 pq[8];
        #pragma unroll
        for (int t = 0; t < 8; ++t) pq[t] = s_pk[g + t];

        // ---- batch: 8 packed csqrts (16 independent scalar streams)
        v2f ku[8], kv[8];
        #pragma unroll
        for (int t = 0; t < 8; ++t)
            csqrt2(q2 - pq[t].w, ku[t], kv[t]);

        // ---- batch: 8 packed ingredient sets
        v2f Ar[8], Ai[8], Er[8], Ei[8], Pr[8], Pi[8];
        #pragma unroll
        for (int t = 7; t >= 0; --t) {
            v2f u1 = ku[t], v1 = kv[t];
            v2f u2 = (t == 7) ? cu : ku[t + 1];
            v2f v2_ = (t == 7) ? cv : kv[t + 1];
            const float4 P = pq[t];   // { 2t*log2e, 2t/(2pi), -2s^2*log2e, xp }

            v2f nr = u1 - u2, ni = v1 - v2_;
            Er[t] = u1 + u2; Ei[t] = v1 + v2_;

            v2f kkr = vfma(u1, u2, -(v1 * v2_));
            v2f kki = vfma(u1, v2_, v1 * u2);
            // roughness magnitude 2^(m2e*kkr) via trans pipe
            v2f zz = P.z * kkr;
            v2f ew; ew.x = fexp2(zz.x); ew.y = fexp2(zz.y);
            // roughness angle (radians) = (m2e*kki)*ln2, |a| <= ~0.1: Taylor
            v2f a  = (P.z * kki) * (v2f)LN2;
            v2f a2 = a * a;
            v2f cw = vfma(a2, (v2f)(-0.5f), (v2f)1.0f);
            v2f sw = a * vfma(a2, (v2f)(-0.16666667f), (v2f)1.0f);
            v2f fr = ew * cw, fi = ew * sw;
            Ar[t] = vfma(nr, fr, -(ni * fi));
            Ai[t] = vfma(nr, fi, ni * fr);

            v2f pm; pm.x = fexp2(P.x * v1.x); pm.y = fexp2(P.x * v1.y);
            float pax = ffract(P.y * u1.x), pay = ffract(P.y * u1.y);
            v2f cp, sp;
            cp.x = fcos_rev(pax); cp.y = fcos_rev(pay);
            sp.x = fsin_rev(pax); sp.y = fsin_rev(pay);
            Pr[t] = pm * cp; Pi[t] = -pm * sp;
        }

        // ---- serial packed Mobius sweep
        #pragma unroll
        for (int t = 7; t >= 0; --t) {
            v2f tnr = vfma(Ar[t], Dr, vfma(-Ai[t], Di, vfma(Er[t], Nr, -(Ei[t] * Ni))));
            v2f tni = vfma(Ar[t], Di, vfma( Ai[t], Dr, vfma(Er[t], Ni,   Ei[t] * Nr)));
            v2f tdr = vfma(Er[t], Dr, vfma(-Ei[t], Di, vfma(Ar[t], Nr, -(Ai[t] * Ni))));
            v2f tdi = vfma(Er[t], Di, vfma( Ei[t], Dr, vfma(Ar[t], Ni,   Ai[t] * Nr)));
            Nr = vfma(tnr, Pr[t], -(tni * Pi[t]));
            Ni = vfma(tnr, Pi[t],   tni * Pr[t]);
            Dr = tdr; Di = tdi;
        }
        {   // exponent renorm (ratio-preserving power of 2), once per 8 layers
            v2f m = vabs(Dr) + vabs(Di);
            int ex = (__float_as_int(m.x) >> 23) & 0xff;
            int ey = (__float_as_int(m.y) >> 23) & 0xff;
            v2f s; s.x = __int_as_float((254 - ex) << 23);
            s.y = __int_as_float((254 - ey) << 23);
            Nr *= s; Ni *= s; Dr *= s; Di *= s;
        }

        cu = ku[0]; cv = kv[0];
        j = g;
    }

    // remainder layers (L % 8) — generic path, not taken for L=64
    while (j > 0) {
        --j;
        const float4 P = s_pk[j];
        v2f u1, v1;
        csqrt2(q2 - P.w, u1, v1);
        v2f nr = u1 - cu, ni = v1 - cv;
        v2f er = u1 + cu, ei = v1 + cv;
        v2f kkr = vfma(u1, cu, -(v1 * cv));
        v2f kki = vfma(u1, cv, v1 * cu);
        v2f zz = P.z * kkr;
        v2f ew; ew.x = fexp2(zz.x); ew.y = fexp2(zz.y);
        v2f a = (P.z * kki) * (v2f)LN2, a2 = a * a;
        v2f cw = vfma(a2, (v2f)(-0.5f), (v2f)1.0f);
        v2f sw = a * vfma(a2, (v2f)(-0.16666667f), (v2f)1.0f);
        v2f fr = ew * cw, fi = ew * sw;
        v2f Arv = vfma(nr, fr, -(ni * fi));
        v2f Aiv = vfma(nr, fi, ni * fr);
        v2f pm; pm.x = fexp2(P.x * v1.x); pm.y = fexp2(P.x * v1.y);
        float pax = ffract(P.y * u1.x), pay = ffract(P.y * u1.y);
        v2f cp, sp;
        cp.x = fcos_rev(pax); sp.x = fsin_rev(pax);
        cp.y = fcos_rev(pay); sp.y = fsin_rev(pay);
        v2f pr = pm * cp, pi = -pm * sp;
        v2f tnr = vfma(Arv, Dr, vfma(-Aiv, Di, vfma(er, Nr, -(ei * Ni))));
        v2f tni = vfma(Arv, Di, vfma( Aiv, Dr, vfma(er, Ni,   ei * Nr)));
        v2f tdr = vfma(er, Dr, vfma(-ei, Di, vfma(Arv, Nr, -(Aiv * Ni))));
        v2f tdi = vfma(er, Di, vfma( ei, Dr, vfma(Arv, Ni,   Aiv * Nr)));
        Nr = vfma(tnr, pr, -(tni * pi));
        Ni = vfma(tnr, pi,   tni * pr);
        Dr = tdr; Di = tdi;
        {
            v2f m = vabs(Dr) + vabs(Di);
            int ex = (__float_as_int(m.x) >> 23) & 0xff;
            int ey = (__float_as_int(m.y) >> 23) & 0xff;
            v2f s; s.x = __int_as_float((254 - ex) << 23);
            s.y = __int_as_float((254 - ey) << 23);
            Nr *= s; Ni *= s; Dr *= s; Di *= s;
        }
        cu = u1; cv = v1;
    }

    v2f d2 = vfma(Dr, Dr, Di * Di);
    v2f n2 = vfma(Nr, Nr, Ni * Ni);
    if (iq0 < Q) out[(size_t)b * Q + iq0] = n2.x * frcp(d2.x);
    if (iq1 < Q) out[(size_t)b * Q + iq1] = n2.y * frcp(d2.y);
}

extern "C" void kernel_launch(void* const* d_in, const int* in_sizes, int n_in,
                              void* d_out, int out_size, void* d_ws, size_t ws_size,
                              hipStream_t stream) {
    const float* q     = (const float*)d_in[0];
    const float* thick = (const float*)d_in[1];
    const float* rough = (const float*)d_in[2];
    const float* sld   = (const float*)d_in[3];
    float* out = (float*)d_out;

    int B = in_sizes[3] - in_sizes[1];   // B*(L+1) - B*L
    int L = in_sizes[1] / B;
    int Q = in_sizes[0] / B;

    dim3 block(256);
    dim3 grid((Q + 511) / 512, B);
    abeles_kernel<<<grid, block, 0, stream>>>(q, thick, rough, sld, out, Q, L);
}